// Round 3
// baseline (647.924 us; speedup 1.0000x reference)
//
#include <hip/hip_runtime.h>
#include <math.h>

// Problem constants (MixtureLowRankRNN)
#define HIDDEN_ 1024
#define RANK_ 4
#define INPUT_ 16
#define T_ 1024
#define BATCH_ 32

#define NTHREADS_ 256
#define NWAVES_ (NTHREADS_ / 64)     // 4 waves, one per SIMD
#define EPT_ (HIDDEN_ / NTHREADS_)   // 4 h-elements per thread
#define CH_ 64                       // x-steps per LDS-staged chunk (64*64B = 4KB)
#define NCH_ (T_ / CH_)              // 16 chunks

typedef float f32x4 __attribute__((ext_vector_type(4)));

__device__ __forceinline__ float fast_exp2(float x) {
#if defined(__has_builtin)
#if __has_builtin(__builtin_amdgcn_exp2f)
    return __builtin_amdgcn_exp2f(x);
#else
    return exp2f(x);
#endif
#else
    return exp2f(x);
#endif
}

__device__ __forceinline__ float fast_rcp(float x) {
#if defined(__has_builtin)
#if __has_builtin(__builtin_amdgcn_rcpf)
    return __builtin_amdgcn_rcpf(x);
#else
    return 1.0f / x;
#endif
#else
    return 1.0f / x;
#endif
}

// tanh(x) = 1 - 2/(exp(2x)+1); exp(2x) = 2^(2*log2(e)*x).
__device__ __forceinline__ float tanh_fast(float x) {
    float e = fast_exp2(x * 2.885390081777926815f); // 2*log2(e)
    return fmaf(-2.0f, fast_rcp(e + 1.0f), 1.0f);
}

// One DPP reduce step: v += dpp_mov(v, ctrl) with old=0, bound_ctrl=1
#define DPP_ADD(v, ctrl)                                                          \
    do {                                                                          \
        int _t = __builtin_amdgcn_update_dpp(0, __float_as_int(v), (ctrl), 0xf,   \
                                             0xf, true);                          \
        (v) += __int_as_float(_t);                                                \
    } while (0)

// Opaque 16B global load: result is an asm output => compiler CANNOT
// rematerialize it from memory inside the loop.
#define GLOAD16(dst, ptr)                                                         \
    asm volatile("global_load_dwordx4 %0, %1, off" : "=v"(dst) : "v"(ptr) : "memory")

// One block per batch element; h entirely in registers (4 elems/thread).
// Output identity: pinv([m|I]) @ [m|I] = I_20, so
//   y_t = 0.9*y_{t-1} + [krec*s_t ; kin*x_t],  s_t = n^T tanh(h_{t-1}).
//
// amdgpu_waves_per_eu(1,1): __launch_bounds__(256,1) sets the waves-per-EU
// RANGE [1,8]; the allocator still spills to chase occupancy (VGPR=68/80/88
// across three builds, all re-loading the ~100-float weight state from L2
// every timestep). Clamping max=1 removes the incentive — actual occupancy
// is already 1 wave/EU (32 blocks on 256 CUs).
__global__ __launch_bounds__(NTHREADS_)
__attribute__((amdgpu_waves_per_eu(1, 1)))
void rnn_scan_kernel(
    const float* __restrict__ x,     // [B, T, 16]
    const float* __restrict__ m,     // [H, 4]
    const float* __restrict__ n,     // [H, 4]
    const float* __restrict__ imat,  // [H, 16]
    float* __restrict__ out)         // [B, T, 20]
{
    const int b    = blockIdx.x;
    const int tid  = threadIdx.x;
    const int wave = tid >> 6;
    const int lane = tid & 63;

    const float kd   = 0.9f;                      // 1 - ALPHA
    const float krec = 0.1f * (500.0f / 1024.0f); // ALPHA * BASE_SCALE / HIDDEN
    const float kin  = 0.1f;                      // ALPHA

    // ---- force-resident weight loads (opaque asm, non-rematerializable) ----
    f32x4 Iv[EPT_][4];
    f32x4 mv[EPT_];
    f32x4 nv[EPT_];
#pragma unroll
    for (int j = 0; j < EPT_; ++j) {
        const int hidx = tid * EPT_ + j;
        const float* ip = imat + hidx * INPUT_;
        GLOAD16(Iv[j][0], ip);
        GLOAD16(Iv[j][1], ip + 4);
        GLOAD16(Iv[j][2], ip + 8);
        GLOAD16(Iv[j][3], ip + 12);
        GLOAD16(mv[j], m + hidx * RANK_);
        GLOAD16(nv[j], n + hidx * RANK_);
    }
    asm volatile("s_waitcnt vmcnt(0)" ::: "memory");

    float h[EPT_];
    float mrs[EPT_][RANK_];    // krec * m row
    float nr[EPT_][RANK_];
    float Irs[EPT_][INPUT_];   // kin * I row
#pragma unroll
    for (int j = 0; j < EPT_; ++j) {
        h[j] = 0.0f;
#pragma unroll
        for (int r = 0; r < RANK_; ++r) {
            mrs[j][r] = krec * mv[j][r];
            nr[j][r]  = nv[j][r];
        }
#pragma unroll
        for (int q = 0; q < 4; ++q) {
#pragma unroll
            for (int e = 0; e < 4; ++e)
                Irs[j][q * 4 + e] = kin * Iv[j][q][e];
        }
    }

    // ---- LDS: cross-wave partials (parity dbuf) + staged x chunks (dbuf) ----
    __shared__ float4 part[2][NWAVES_];
    __shared__ float xs[2][CH_ * INPUT_];   // 2 x 4KB

    const float* xb = x + (size_t)b * T_ * INPUT_;
    float* ob = out + (size_t)b * T_ * (RANK_ + INPUT_);

    // Prologue staging: chunk 0 -> xs[0]; chunk 1 preloaded into xstage regs.
    {
        float4 c0 = *(const float4*)(xb + tid * 4);           // 256*16B = 4KB
        *(float4*)&xs[0][tid * 4] = c0;
    }
    float4 xstage = *(const float4*)(xb + CH_ * INPUT_ + tid * 4);

    float y = 0.0f;  // output accumulator (tid < 20)
    const int yoff = (tid >= 4 && tid < 20) ? (tid - 4) : 0;

    for (int t = 0; t < T_; ++t) {
        // --- tanh(h) + rank partials (VALU only) ---
        float th[EPT_];
#pragma unroll
        for (int j = 0; j < EPT_; ++j) th[j] = tanh_fast(h[j]);

        float p0 = th[0] * nr[0][0], p1 = th[0] * nr[0][1];
        float p2 = th[0] * nr[0][2], p3 = th[0] * nr[0][3];
#pragma unroll
        for (int j = 1; j < EPT_; ++j) {
            p0 = fmaf(th[j], nr[j][0], p0);
            p1 = fmaf(th[j], nr[j][1], p1);
            p2 = fmaf(th[j], nr[j][2], p2);
            p3 = fmaf(th[j], nr[j][3], p3);
        }

        // --- wave reduce via DPP, level-major for ILP across 4 ranks ---
        DPP_ADD(p0, 0x111); DPP_ADD(p1, 0x111); DPP_ADD(p2, 0x111); DPP_ADD(p3, 0x111);
        DPP_ADD(p0, 0x112); DPP_ADD(p1, 0x112); DPP_ADD(p2, 0x112); DPP_ADD(p3, 0x112);
        DPP_ADD(p0, 0x114); DPP_ADD(p1, 0x114); DPP_ADD(p2, 0x114); DPP_ADD(p3, 0x114);
        DPP_ADD(p0, 0x118); DPP_ADD(p1, 0x118); DPP_ADD(p2, 0x118); DPP_ADD(p3, 0x118);
        DPP_ADD(p0, 0x142); DPP_ADD(p1, 0x142); DPP_ADD(p2, 0x142); DPP_ADD(p3, 0x142);
        DPP_ADD(p0, 0x143); DPP_ADD(p1, 0x143); DPP_ADD(p2, 0x143); DPP_ADD(p3, 0x143);

        if (lane == 63) part[t & 1][wave] = make_float4(p0, p1, p2, p3);

        // Raw barrier: LDS-visibility wait ONLY (no vmcnt drain — x staging
        // loads and y stores stay in flight across steps).
        asm volatile("s_waitcnt lgkmcnt(0)\n\ts_barrier" ::: "memory");

        // --- chunk staging (post-barrier) ---
        if ((t & (CH_ - 1)) == 0) {
            const int c = t >> 6;
            *(float4*)&xs[(c + 1) & 1][tid * 4] = xstage;   // chunk c+1
            const int cl = (c + 2 < NCH_) ? (c + 2) : (NCH_ - 1);
            xstage = *(const float4*)(xb + cl * CH_ * INPUT_ + tid * 4);
        }

        // --- issue x_t reads (LDS broadcast), then cross-wave partials ---
        const float* xsp = &xs[(t >> 6) & 1][(t & 63) * INPUT_];
        const float4 xa = ((const float4*)xsp)[0];
        const float4 xbv = ((const float4*)xsp)[1];
        const float4 xc = ((const float4*)xsp)[2];
        const float4 xd = ((const float4*)xsp)[3];
        const float xyv = xsp[yoff];

        const float4 q0 = part[t & 1][0];
        const float4 q1 = part[t & 1][1];
        const float4 q2 = part[t & 1][2];
        const float4 q3 = part[t & 1][3];

        // --- ax = (kin*I) @ x_t : fills the ds_read latency window ---
        float ax[EPT_];
#pragma unroll
        for (int j = 0; j < EPT_; ++j) {
            float a = xa.x * Irs[j][0];
            float c = xa.y * Irs[j][1];
            a = fmaf(xa.z, Irs[j][2], a);   c = fmaf(xa.w, Irs[j][3], c);
            a = fmaf(xbv.x, Irs[j][4], a);  c = fmaf(xbv.y, Irs[j][5], c);
            a = fmaf(xbv.z, Irs[j][6], a);  c = fmaf(xbv.w, Irs[j][7], c);
            a = fmaf(xc.x, Irs[j][8], a);   c = fmaf(xc.y, Irs[j][9], c);
            a = fmaf(xc.z, Irs[j][10], a);  c = fmaf(xc.w, Irs[j][11], c);
            a = fmaf(xd.x, Irs[j][12], a);  c = fmaf(xd.y, Irs[j][13], c);
            a = fmaf(xd.z, Irs[j][14], a);  c = fmaf(xd.w, Irs[j][15], c);
            ax[j] = a + c;
        }

        // --- combine partials -> s ---
        const float s0 = (q0.x + q1.x) + (q2.x + q3.x);
        const float s1 = (q0.y + q1.y) + (q2.y + q3.y);
        const float s2 = (q0.z + q1.z) + (q2.z + q3.z);
        const float s3 = (q0.w + q1.w) + (q2.w + q3.w);

        // --- h <- kd*h + mrs@s + ax  (tree: ~16cy from s) ---
#pragma unroll
        for (int j = 0; j < EPT_; ++j) {
            float a01 = fmaf(s1, mrs[j][1], fmaf(s0, mrs[j][0], ax[j]));
            float a23 = fmaf(s3, mrs[j][3], s2 * mrs[j][2]);
            h[j] = fmaf(kd, h[j], a01 + a23);
        }

        // --- y_t = kd*y_{t-1} + [krec*s ; kin*x_t]  (lanes 0..19 of wave 0) ---
        if (tid < 20) {
            float drive;
            if (tid < 4) {
                float sv = (tid == 0) ? s0 : (tid == 1) ? s1 : (tid == 2) ? s2 : s3;
                drive = krec * sv;
            } else {
                drive = kin * xyv;
            }
            y = fmaf(kd, y, drive);
            ob[t * 20 + tid] = y;   // fire-and-forget: never drained in-loop
        }
    }
}

extern "C" void kernel_launch(void* const* d_in, const int* in_sizes, int n_in,
                              void* d_out, int out_size, void* d_ws, size_t ws_size,
                              hipStream_t stream) {
    const float* x    = (const float*)d_in[0];
    const float* m    = (const float*)d_in[1];
    const float* n    = (const float*)d_in[2];
    const float* imat = (const float*)d_in[3];
    float* out = (float*)d_out;

    rnn_scan_kernel<<<dim3(BATCH_), dim3(NTHREADS_), 0, stream>>>(x, m, n, imat, out);
}

// Round 4
// 570.433 us; speedup vs baseline: 1.1358x; 1.1358x over previous
//
#include <hip/hip_runtime.h>
#include <math.h>

// Problem constants (MixtureLowRankRNN)
#define HIDDEN_ 1024
#define RANK_ 4
#define INPUT_ 16
#define T_ 1024
#define BATCH_ 32

#define NTHREADS_ 256
#define NWAVES_ (NTHREADS_ / 64)     // 4 waves, one per SIMD
#define EPT_ (HIDDEN_ / NTHREADS_)   // 4 h-elements per thread
#define CH_ 64                       // x-steps per LDS-staged chunk (64*64B = 4KB)
#define NCH_ (T_ / CH_)              // 16 chunks

#define PRE_BLOCKS_ 2048
#define ROWS_ (BATCH_ * T_)              // 32768 rows of x
#define PASSES_ (ROWS_ / PRE_BLOCKS_)    // 16

typedef float f32x4 __attribute__((ext_vector_type(4)));

__device__ __forceinline__ float fast_exp2(float x) {
#if defined(__has_builtin)
#if __has_builtin(__builtin_amdgcn_exp2f)
    return __builtin_amdgcn_exp2f(x);
#else
    return exp2f(x);
#endif
#else
    return exp2f(x);
#endif
}

__device__ __forceinline__ float fast_rcp(float x) {
#if defined(__has_builtin)
#if __has_builtin(__builtin_amdgcn_rcpf)
    return __builtin_amdgcn_rcpf(x);
#else
    return 1.0f / x;
#endif
#else
    return 1.0f / x;
#endif
}

// tanh(x) = 1 - 2/(exp(2x)+1); exp(2x) = 2^(2*log2(e)*x).
__device__ __forceinline__ float tanh_fast(float x) {
    float e = fast_exp2(x * 2.885390081777926815f); // 2*log2(e)
    return fmaf(-2.0f, fast_rcp(e + 1.0f), 1.0f);
}

// One DPP reduce step: v += dpp_mov(v, ctrl) with old=0, bound_ctrl=1
#define DPP_ADD(v, ctrl)                                                          \
    do {                                                                          \
        int _t = __builtin_amdgcn_update_dpp(0, __float_as_int(v), (ctrl), 0xf,   \
                                             0xf, true);                          \
        (v) += __int_as_float(_t);                                                \
    } while (0)

// ---------------------------------------------------------------------------
// Kernel 1: u[row, h] = kin * sum_i I[h,i] * x[row,i]   (row = b*T + t)
// Fully parallel feed-forward GEMM — uses all CUs, memory-bound on the
// 128 MB u write. Removes 68 VALU instrs/step from the serial scan wave.
// ---------------------------------------------------------------------------
__global__ __launch_bounds__(NTHREADS_, 2) void precompute_u(
    const float* __restrict__ x,     // [ROWS_, 16]
    const float* __restrict__ imat,  // [H, 16]
    float* __restrict__ u)           // [ROWS_, H]
{
    const int tid = threadIdx.x;
    const int bid = blockIdx.x;
    const float kin = 0.1f;

    // This thread owns h = 4*tid .. 4*tid+3 for every row it touches.
    // I rows held in registers across all passes (64 VGPRs), kin folded in.
    float Ir[4][INPUT_];
#pragma unroll
    for (int r = 0; r < 4; ++r) {
        const float* ip = imat + (4 * tid + r) * INPUT_;
#pragma unroll
        for (int q = 0; q < 4; ++q) {
            const float4 v = *(const float4*)(ip + 4 * q);
            Ir[r][q*4+0] = kin * v.x; Ir[r][q*4+1] = kin * v.y;
            Ir[r][q*4+2] = kin * v.z; Ir[r][q*4+3] = kin * v.w;
        }
    }

    for (int p = 0; p < PASSES_; ++p) {
        const int row = p * PRE_BLOCKS_ + bid;
        const float* xr = x + (size_t)row * INPUT_;
        float xv[INPUT_];
#pragma unroll
        for (int q = 0; q < 4; ++q) {
            const float4 v = ((const float4*)xr)[q];   // wave-uniform
            xv[q*4+0] = v.x; xv[q*4+1] = v.y; xv[q*4+2] = v.z; xv[q*4+3] = v.w;
        }
        float4 acc;
        float a[4];
#pragma unroll
        for (int r = 0; r < 4; ++r) {
            float s0 = xv[0] * Ir[r][0];
            float s1 = xv[1] * Ir[r][1];
#pragma unroll
            for (int i = 2; i < INPUT_; i += 2) {
                s0 = fmaf(xv[i],     Ir[r][i],     s0);
                s1 = fmaf(xv[i + 1], Ir[r][i + 1], s1);
            }
            a[r] = s0 + s1;
        }
        acc.x = a[0]; acc.y = a[1]; acc.z = a[2]; acc.w = a[3];
        *(float4*)(u + (size_t)row * HIDDEN_ + 4 * tid) = acc;  // coalesced
    }
}

// ---------------------------------------------------------------------------
// Kernel 2: the serial scan. One block per batch element, 1 wave/SIMD.
//   y_t = 0.9*y_{t-1} + [krec*s_t ; kin*x_t],  s_t = n^T tanh(h_{t-1}),
//   h_t = 0.9*h_{t-1} + (krec*m) s_t + u_t     (u precomputed).
// ---------------------------------------------------------------------------
__global__ __launch_bounds__(NTHREADS_)
__attribute__((amdgpu_waves_per_eu(1, 1)))
void rnn_scan_kernel(
    const float* __restrict__ x,     // [B, T, 16]
    const float* __restrict__ m,     // [H, 4]
    const float* __restrict__ n,     // [H, 4]
    const float* __restrict__ u,     // [B, T, H] precomputed
    float* __restrict__ out)         // [B, T, 20]
{
    const int b    = blockIdx.x;
    const int tid  = threadIdx.x;
    const int wave = tid >> 6;
    const int lane = tid & 63;

    const float kd   = 0.9f;                      // 1 - ALPHA
    const float krec = 0.1f * (500.0f / 1024.0f); // ALPHA * BASE_SCALE / HIDDEN

    float h[EPT_];
    float mrs[EPT_][RANK_];    // krec * m row
    float nr[EPT_][RANK_];
#pragma unroll
    for (int j = 0; j < EPT_; ++j) {
        const int hidx = tid * EPT_ + j;
        h[j] = 0.0f;
        const float4 mv = *(const float4*)(m + hidx * RANK_);
        mrs[j][0] = krec * mv.x; mrs[j][1] = krec * mv.y;
        mrs[j][2] = krec * mv.z; mrs[j][3] = krec * mv.w;
        const float4 nv = *(const float4*)(n + hidx * RANK_);
        nr[j][0] = nv.x; nr[j][1] = nv.y; nr[j][2] = nv.z; nr[j][3] = nv.w;
    }

    // ---- LDS: cross-wave partials (parity dbuf) + staged x chunks (dbuf) ----
    __shared__ float4 part[2][NWAVES_];
    __shared__ float xs[2][CH_ * INPUT_];   // 2 x 4KB (y-path x drive)

    const float* xb = x + (size_t)b * T_ * INPUT_;
    const float* ub = u + (size_t)b * T_ * HIDDEN_ + tid * EPT_;
    float* ob = out + (size_t)b * T_ * (RANK_ + INPUT_);

    // Prologue: stage x chunk 0 -> xs[0]; chunk 1 in regs; prefetch u[0..3].
    {
        float4 c0 = *(const float4*)(xb + tid * 4);
        *(float4*)&xs[0][tid * 4] = c0;
    }
    float4 xstage = *(const float4*)(xb + CH_ * INPUT_ + tid * 4);

    float4 upf[4];
#pragma unroll
    for (int k = 0; k < 4; ++k)
        upf[k] = *(const float4*)(ub + (size_t)k * HIDDEN_);

    float y = 0.0f;  // output accumulator (tid < 20)
    const int yoff = (tid >= 4 && tid < 20) ? (tid - 4) : 0;

#pragma unroll 4
    for (int t = 0; t < T_; ++t) {
        // --- tanh(h) + rank partials (VALU only) ---
        float th[EPT_];
#pragma unroll
        for (int j = 0; j < EPT_; ++j) th[j] = tanh_fast(h[j]);

        float p0 = th[0] * nr[0][0], p1 = th[0] * nr[0][1];
        float p2 = th[0] * nr[0][2], p3 = th[0] * nr[0][3];
#pragma unroll
        for (int j = 1; j < EPT_; ++j) {
            p0 = fmaf(th[j], nr[j][0], p0);
            p1 = fmaf(th[j], nr[j][1], p1);
            p2 = fmaf(th[j], nr[j][2], p2);
            p3 = fmaf(th[j], nr[j][3], p3);
        }

        // --- wave reduce via DPP, level-major for ILP across 4 ranks ---
        DPP_ADD(p0, 0x111); DPP_ADD(p1, 0x111); DPP_ADD(p2, 0x111); DPP_ADD(p3, 0x111);
        DPP_ADD(p0, 0x112); DPP_ADD(p1, 0x112); DPP_ADD(p2, 0x112); DPP_ADD(p3, 0x112);
        DPP_ADD(p0, 0x114); DPP_ADD(p1, 0x114); DPP_ADD(p2, 0x114); DPP_ADD(p3, 0x114);
        DPP_ADD(p0, 0x118); DPP_ADD(p1, 0x118); DPP_ADD(p2, 0x118); DPP_ADD(p3, 0x118);
        DPP_ADD(p0, 0x142); DPP_ADD(p1, 0x142); DPP_ADD(p2, 0x142); DPP_ADD(p3, 0x142);
        DPP_ADD(p0, 0x143); DPP_ADD(p1, 0x143); DPP_ADD(p2, 0x143); DPP_ADD(p3, 0x143);

        if (lane == 63) part[t & 1][wave] = make_float4(p0, p1, p2, p3);

        // Raw barrier: LDS-visibility wait ONLY (no vmcnt drain — u prefetch,
        // x staging loads and y stores stay in flight across steps).
        asm volatile("s_waitcnt lgkmcnt(0)\n\ts_barrier" ::: "memory");

        // --- x chunk staging for the y path (every 64 steps) ---
        if ((t & (CH_ - 1)) == 0) {
            const int c = t >> 6;
            *(float4*)&xs[(c + 1) & 1][tid * 4] = xstage;   // chunk c+1
            const int cl = (c + 2 < NCH_) ? (c + 2) : (NCH_ - 1);
            xstage = *(const float4*)(xb + cl * CH_ * INPUT_ + tid * 4);
        }

        // --- read cross-wave partials + this step's u + y-drive x ---
        const float4 q0 = part[t & 1][0];
        const float4 q1 = part[t & 1][1];
        const float4 q2 = part[t & 1][2];
        const float4 q3 = part[t & 1][3];
        const float xyv = xs[(t >> 6) & 1][(t & 63) * INPUT_ + yoff];

        const float4 uv = upf[t & 3];   // prefetched 4 steps ago
        {   // refill slot with u[t+4] (dummy re-read near the tail)
            const int tn = (t + 4 < T_) ? (t + 4) : t;
            upf[t & 3] = *(const float4*)(ub + (size_t)tn * HIDDEN_);
        }

        // --- combine partials -> s ---
        const float s0 = (q0.x + q1.x) + (q2.x + q3.x);
        const float s1 = (q0.y + q1.y) + (q2.y + q3.y);
        const float s2 = (q0.z + q1.z) + (q2.z + q3.z);
        const float s3 = (q0.w + q1.w) + (q2.w + q3.w);

        // --- h <- kd*h + mrs@s + u_t  (short tree from s) ---
        const float uq[4] = {uv.x, uv.y, uv.z, uv.w};
#pragma unroll
        for (int j = 0; j < EPT_; ++j) {
            float a01 = fmaf(s1, mrs[j][1], fmaf(s0, mrs[j][0], uq[j]));
            float a23 = fmaf(s3, mrs[j][3], s2 * mrs[j][2]);
            h[j] = fmaf(kd, h[j], a01 + a23);
        }

        // --- y_t = kd*y_{t-1} + [krec*s ; kin*x_t]  (lanes 0..19 of wave 0) ---
        if (tid < 20) {
            float drive;
            if (tid < 4) {
                float sv = (tid == 0) ? s0 : (tid == 1) ? s1 : (tid == 2) ? s2 : s3;
                drive = krec * sv;
            } else {
                drive = 0.1f * xyv;   // kin
            }
            y = fmaf(kd, y, drive);
            ob[t * 20 + tid] = y;   // fire-and-forget: never drained in-loop
        }
    }
}

// ---------------------------------------------------------------------------
// Fallback (no workspace): R2-style single kernel computing I@x in-loop.
// ---------------------------------------------------------------------------
__global__ __launch_bounds__(NTHREADS_)
__attribute__((amdgpu_waves_per_eu(1, 1)))
void rnn_scan_fallback(
    const float* __restrict__ x, const float* __restrict__ m,
    const float* __restrict__ n, const float* __restrict__ imat,
    float* __restrict__ out)
{
    const int b    = blockIdx.x;
    const int tid  = threadIdx.x;
    const int wave = tid >> 6;
    const int lane = tid & 63;
    const float kd = 0.9f, krec = 0.1f * (500.0f / 1024.0f), kin = 0.1f;

    float h[EPT_], mrs[EPT_][RANK_], nr[EPT_][RANK_], Irs[EPT_][INPUT_];
#pragma unroll
    for (int j = 0; j < EPT_; ++j) {
        const int hidx = tid * EPT_ + j;
        h[j] = 0.0f;
        const float4 mv = *(const float4*)(m + hidx * RANK_);
        mrs[j][0] = krec * mv.x; mrs[j][1] = krec * mv.y;
        mrs[j][2] = krec * mv.z; mrs[j][3] = krec * mv.w;
        const float4 nv = *(const float4*)(n + hidx * RANK_);
        nr[j][0] = nv.x; nr[j][1] = nv.y; nr[j][2] = nv.z; nr[j][3] = nv.w;
#pragma unroll
        for (int q = 0; q < 4; ++q) {
            const float4 iv = *(const float4*)(imat + hidx * INPUT_ + q * 4);
            Irs[j][q*4+0] = kin * iv.x; Irs[j][q*4+1] = kin * iv.y;
            Irs[j][q*4+2] = kin * iv.z; Irs[j][q*4+3] = kin * iv.w;
        }
    }
    __shared__ float4 part[2][NWAVES_];
    __shared__ float xs[2][CH_ * INPUT_];
    const float* xb = x + (size_t)b * T_ * INPUT_;
    float* ob = out + (size_t)b * T_ * (RANK_ + INPUT_);
    {
        float4 c0 = *(const float4*)(xb + tid * 4);
        *(float4*)&xs[0][tid * 4] = c0;
    }
    float4 xstage = *(const float4*)(xb + CH_ * INPUT_ + tid * 4);
    float y = 0.0f;
    const int yoff = (tid >= 4 && tid < 20) ? (tid - 4) : 0;

    for (int t = 0; t < T_; ++t) {
        float th[EPT_];
#pragma unroll
        for (int j = 0; j < EPT_; ++j) th[j] = tanh_fast(h[j]);
        float p0 = th[0] * nr[0][0], p1 = th[0] * nr[0][1];
        float p2 = th[0] * nr[0][2], p3 = th[0] * nr[0][3];
#pragma unroll
        for (int j = 1; j < EPT_; ++j) {
            p0 = fmaf(th[j], nr[j][0], p0); p1 = fmaf(th[j], nr[j][1], p1);
            p2 = fmaf(th[j], nr[j][2], p2); p3 = fmaf(th[j], nr[j][3], p3);
        }
        DPP_ADD(p0, 0x111); DPP_ADD(p1, 0x111); DPP_ADD(p2, 0x111); DPP_ADD(p3, 0x111);
        DPP_ADD(p0, 0x112); DPP_ADD(p1, 0x112); DPP_ADD(p2, 0x112); DPP_ADD(p3, 0x112);
        DPP_ADD(p0, 0x114); DPP_ADD(p1, 0x114); DPP_ADD(p2, 0x114); DPP_ADD(p3, 0x114);
        DPP_ADD(p0, 0x118); DPP_ADD(p1, 0x118); DPP_ADD(p2, 0x118); DPP_ADD(p3, 0x118);
        DPP_ADD(p0, 0x142); DPP_ADD(p1, 0x142); DPP_ADD(p2, 0x142); DPP_ADD(p3, 0x142);
        DPP_ADD(p0, 0x143); DPP_ADD(p1, 0x143); DPP_ADD(p2, 0x143); DPP_ADD(p3, 0x143);
        if (lane == 63) part[t & 1][wave] = make_float4(p0, p1, p2, p3);
        asm volatile("s_waitcnt lgkmcnt(0)\n\ts_barrier" ::: "memory");
        if ((t & (CH_ - 1)) == 0) {
            const int c = t >> 6;
            *(float4*)&xs[(c + 1) & 1][tid * 4] = xstage;
            const int cl = (c + 2 < NCH_) ? (c + 2) : (NCH_ - 1);
            xstage = *(const float4*)(xb + cl * CH_ * INPUT_ + tid * 4);
        }
        const float* xsp = &xs[(t >> 6) & 1][(t & 63) * INPUT_];
        const float4 xa = ((const float4*)xsp)[0];
        const float4 xbv = ((const float4*)xsp)[1];
        const float4 xc = ((const float4*)xsp)[2];
        const float4 xd = ((const float4*)xsp)[3];
        const float xyv = xsp[yoff];
        const float4 q0 = part[t & 1][0];
        const float4 q1 = part[t & 1][1];
        const float4 q2 = part[t & 1][2];
        const float4 q3 = part[t & 1][3];
        float ax[EPT_];
#pragma unroll
        for (int j = 0; j < EPT_; ++j) {
            float a = xa.x * Irs[j][0];
            float c = xa.y * Irs[j][1];
            a = fmaf(xa.z, Irs[j][2], a);   c = fmaf(xa.w, Irs[j][3], c);
            a = fmaf(xbv.x, Irs[j][4], a);  c = fmaf(xbv.y, Irs[j][5], c);
            a = fmaf(xbv.z, Irs[j][6], a);  c = fmaf(xbv.w, Irs[j][7], c);
            a = fmaf(xc.x, Irs[j][8], a);   c = fmaf(xc.y, Irs[j][9], c);
            a = fmaf(xc.z, Irs[j][10], a);  c = fmaf(xc.w, Irs[j][11], c);
            a = fmaf(xd.x, Irs[j][12], a);  c = fmaf(xd.y, Irs[j][13], c);
            a = fmaf(xd.z, Irs[j][14], a);  c = fmaf(xd.w, Irs[j][15], c);
            ax[j] = a + c;
        }
        const float s0 = (q0.x + q1.x) + (q2.x + q3.x);
        const float s1 = (q0.y + q1.y) + (q2.y + q3.y);
        const float s2 = (q0.z + q1.z) + (q2.z + q3.z);
        const float s3 = (q0.w + q1.w) + (q2.w + q3.w);
#pragma unroll
        for (int j = 0; j < EPT_; ++j) {
            float a01 = fmaf(s1, mrs[j][1], fmaf(s0, mrs[j][0], ax[j]));
            float a23 = fmaf(s3, mrs[j][3], s2 * mrs[j][2]);
            h[j] = fmaf(kd, h[j], a01 + a23);
        }
        if (tid < 20) {
            float drive;
            if (tid < 4) {
                float sv = (tid == 0) ? s0 : (tid == 1) ? s1 : (tid == 2) ? s2 : s3;
                drive = krec * sv;
            } else {
                drive = kin * xyv;
            }
            y = fmaf(kd, y, drive);
            ob[t * 20 + tid] = y;
        }
    }
}

extern "C" void kernel_launch(void* const* d_in, const int* in_sizes, int n_in,
                              void* d_out, int out_size, void* d_ws, size_t ws_size,
                              hipStream_t stream) {
    const float* x    = (const float*)d_in[0];
    const float* m    = (const float*)d_in[1];
    const float* n    = (const float*)d_in[2];
    const float* imat = (const float*)d_in[3];
    float* out = (float*)d_out;

    const size_t u_bytes = (size_t)BATCH_ * T_ * HIDDEN_ * sizeof(float); // 128 MB
    if (d_ws != nullptr && ws_size >= u_bytes) {
        float* u = (float*)d_ws;
        precompute_u<<<dim3(PRE_BLOCKS_), dim3(NTHREADS_), 0, stream>>>(x, imat, u);
        rnn_scan_kernel<<<dim3(BATCH_), dim3(NTHREADS_), 0, stream>>>(x, m, n, u, out);
    } else {
        rnn_scan_fallback<<<dim3(BATCH_), dim3(NTHREADS_), 0, stream>>>(x, m, n, imat, out);
    }
}